// Round 5
// baseline (778.008 us; speedup 1.0000x reference)
//
#include <hip/hip_runtime.h>
#include <hip/hip_bf16.h>

// Problem constants (match reference)
#define N_NODES 50000
#define N_EDGES 800000
#define IN_C 256
#define HID_C 128
#define OUT_C 64

#define NB_SCAN ((N_NODES + 255) / 256)   // 196 blocks of 256 nodes

typedef __attribute__((ext_vector_type(8))) short bf16x8;
typedef __attribute__((ext_vector_type(4))) float f32x4;

__device__ __forceinline__ ushort f2bf(float f) {
    uint u = __float_as_uint(f);
    u += 0x7fff + ((u >> 16) & 1);   // round-to-nearest-even
    return (ushort)(u >> 16);
}
__device__ __forceinline__ float bf2f(ushort h) {
    return __uint_as_float(((uint)h) << 16);
}

// ---------------------------------------------------------------------------
// Graph preprocessing
// ---------------------------------------------------------------------------

__global__ __launch_bounds__(256) void init_deg_kernel(int* __restrict__ degi) {
    int i = blockIdx.x * 256 + threadIdx.x;
    if (i < N_NODES) degi[i] = 1;  // self-loop
}

__global__ __launch_bounds__(256) void count_deg_kernel(const int* __restrict__ dst,
                                                        int* __restrict__ degi) {
    int e = blockIdx.x * 256 + threadIdx.x;
    if (e < N_EDGES) atomicAdd(&degi[dst[e]], 1);
}

__global__ __launch_bounds__(256) void deg_partial_kernel(const int* __restrict__ degi,
                                                          int* __restrict__ partials) {
    __shared__ int s[256];
    int t = threadIdx.x;
    int i = blockIdx.x * 256 + t;
    s[t] = (i < N_NODES) ? degi[i] : 0;
    __syncthreads();
#pragma unroll
    for (int off = 128; off > 0; off >>= 1) {
        if (t < off) s[t] += s[t + off];
        __syncthreads();
    }
    if (t == 0) partials[blockIdx.x] = s[0];
}

__global__ __launch_bounds__(256) void scan_partials_kernel(const int* __restrict__ partials,
                                                            int* __restrict__ partial_off,
                                                            int* __restrict__ row_ptr) {
    __shared__ int s[256];
    int t = threadIdx.x;
    s[t] = (t < NB_SCAN) ? partials[t] : 0;
    __syncthreads();
#pragma unroll
    for (int off = 1; off < 256; off <<= 1) {
        int x = s[t];
        int add = (t >= off) ? s[t - off] : 0;
        __syncthreads();
        s[t] = x + add;
        __syncthreads();
    }
    if (t < NB_SCAN) partial_off[t] = (t == 0) ? 0 : s[t - 1];
    if (t == 255) row_ptr[N_NODES] = s[255];
}

__global__ __launch_bounds__(256) void scan_final_kernel(const int* __restrict__ degi,
                                                         const int* __restrict__ partial_off,
                                                         int* __restrict__ row_ptr,
                                                         int* __restrict__ cursor,
                                                         float* __restrict__ dis) {
    __shared__ int s[256];
    int t = threadIdx.x;
    int i = blockIdx.x * 256 + t;
    int d = (i < N_NODES) ? degi[i] : 0;
    s[t] = d;
    __syncthreads();
#pragma unroll
    for (int off = 1; off < 256; off <<= 1) {
        int x = s[t];
        int add = (t >= off) ? s[t - off] : 0;
        __syncthreads();
        s[t] = x + add;
        __syncthreads();
    }
    if (i < N_NODES) {
        int excl = partial_off[blockIdx.x] + s[t] - d;
        row_ptr[i] = excl;
        cursor[i] = excl;
        dis[i] = rsqrtf((float)d);
    }
}

// 4B scatter per edge: src index only (norm is factorized via dis)
__global__ __launch_bounds__(256) void scatter_kernel(const int* __restrict__ src,
                                                      const int* __restrict__ dst,
                                                      int* __restrict__ cursor,
                                                      int* __restrict__ csr_src) {
    int i = blockIdx.x * 256 + threadIdx.x;
    if (i >= N_EDGES + N_NODES) return;
    int s, d;
    if (i < N_EDGES) {
        s = src[i];
        d = dst[i];
    } else {
        s = d = i - N_EDGES;
    }
    int slot = atomicAdd(&cursor[d], 1);
    csr_src[slot] = s;
}

// ---------------------------------------------------------------------------
// Weight packing: W[K][N] fp32 -> fragment-ordered bf16 hi/lo
// layout: Pk[kt][ct][lane][j], element = W[kt*32 + (lane>>4)*8 + j][ct*16 + (lane&15)]
// ---------------------------------------------------------------------------

__global__ __launch_bounds__(64) void pack_w_kernel(const float* __restrict__ W,
                                                    ushort* __restrict__ Ph,
                                                    ushort* __restrict__ Pl,
                                                    int K, int N) {
    int lane = threadIdx.x;
    int CT = N / 16;
    int ct = blockIdx.x % CT;
    int kt = blockIdx.x / CT;
    int lr = lane & 15, lg = lane >> 4;
    size_t base = ((size_t)blockIdx.x * 64 + lane) * 8;
#pragma unroll
    for (int j = 0; j < 8; j++) {
        float w = W[(size_t)(kt * 32 + lg * 8 + j) * N + ct * 16 + lr];
        ushort h = f2bf(w);
        ushort lo = f2bf(w - bf2f(h));
        Ph[base + j] = h;
        Pl[base + j] = lo;
    }
}

// ---------------------------------------------------------------------------
// LDS-free MFMA GEMM with 3-term bf16 split.
// C[M][N] = A[M][K] @ W[K][N]. Wave owns 32 rows x N cols; block = 128 rows.
// OUT_MODE: 0 = fp32 + bias (row-major), 1 = bf16 hi/lo + bias (row-major),
//           2 = fp32 * dis[row], SLICE-MAJOR layout gs[ct][M][16]
// ---------------------------------------------------------------------------

template <int K, int N, int OUT_MODE, bool AF32>
__global__ __launch_bounds__(256) void gemm_mfma_kernel(
    const float* __restrict__ Af, const ushort* __restrict__ Ahi,
    const ushort* __restrict__ Alo, const ushort* __restrict__ Wph,
    const ushort* __restrict__ Wpl, const float* __restrict__ bias,
    const float* __restrict__ disp, float* __restrict__ Cf,
    ushort* __restrict__ CHi, ushort* __restrict__ CLo, int M) {
    constexpr int CT = N / 16;
    constexpr int KT = K / 32;

    const int wid = threadIdx.x >> 6;
    const int lane = threadIdx.x & 63;
    const int lr = lane & 15;
    const int lg = lane >> 4;
    const int row_base = blockIdx.x * 128 + wid * 32;

    f32x4 acc[2][CT];
#pragma unroll
    for (int rt = 0; rt < 2; rt++)
#pragma unroll
        for (int ct = 0; ct < CT; ct++) acc[rt][ct] = (f32x4){0.f, 0.f, 0.f, 0.f};

    for (int kt = 0; kt < KT; kt++) {
        const int kof = kt * 32 + lg * 8;
        bf16x8 ah[2], al[2];
#pragma unroll
        for (int rt = 0; rt < 2; rt++) {
            int r = row_base + rt * 16 + lr;
            if (r >= M) r = M - 1;  // clamp; result discarded on store
            if (AF32) {
                const float* ap = &Af[(size_t)r * K + kof];
                float4 v0 = *(const float4*)ap;
                float4 v1 = *(const float4*)(ap + 4);
                float av[8] = {v0.x, v0.y, v0.z, v0.w, v1.x, v1.y, v1.z, v1.w};
#pragma unroll
                for (int j = 0; j < 8; j++) {
                    ushort h = f2bf(av[j]);
                    ushort lo = f2bf(av[j] - bf2f(h));
                    ah[rt][j] = (short)h;
                    al[rt][j] = (short)lo;
                }
            } else {
                ah[rt] = *(const bf16x8*)&Ahi[(size_t)r * K + kof];
                al[rt] = *(const bf16x8*)&Alo[(size_t)r * K + kof];
            }
        }
        const ushort* bh = &Wph[(size_t)kt * CT * 512 + (size_t)lane * 8];
        const ushort* bl = &Wpl[(size_t)kt * CT * 512 + (size_t)lane * 8];
#pragma unroll
        for (int ct = 0; ct < CT; ct++) {
            bf16x8 bhv = *(const bf16x8*)(bh + ct * 512);
            bf16x8 blv = *(const bf16x8*)(bl + ct * 512);
#pragma unroll
            for (int rt = 0; rt < 2; rt++) {
                acc[rt][ct] = __builtin_amdgcn_mfma_f32_16x16x32_bf16(ah[rt], bhv, acc[rt][ct], 0, 0, 0);
                acc[rt][ct] = __builtin_amdgcn_mfma_f32_16x16x32_bf16(al[rt], bhv, acc[rt][ct], 0, 0, 0);
                acc[rt][ct] = __builtin_amdgcn_mfma_f32_16x16x32_bf16(ah[rt], blv, acc[rt][ct], 0, 0, 0);
            }
        }
    }

    // Epilogue: D[row][col], row = rt*16 + lg*4 + j, col = ct*16 + lr
#pragma unroll
    for (int rt = 0; rt < 2; rt++)
#pragma unroll
        for (int ct = 0; ct < CT; ct++)
#pragma unroll
            for (int j = 0; j < 4; j++) {
                int r = row_base + rt * 16 + lg * 4 + j;
                if (r >= M) continue;
                int c = ct * 16 + lr;
                float v = acc[rt][ct][j];
                if (OUT_MODE == 2) {
                    // slice-major: gs[ct][r][lr], scaled by dis[r]
                    Cf[(size_t)ct * M * 16 + (size_t)r * 16 + lr] = v * disp[r];
                } else {
                    v += bias[c];
                    if (OUT_MODE == 1) {
                        ushort h = f2bf(v);
                        ushort lo = f2bf(v - bf2f(h));
                        CHi[(size_t)r * N + c] = h;
                        CLo[(size_t)r * N + c] = lo;
                    } else {
                        Cf[(size_t)r * N + c] = v;
                    }
                }
            }
}

// ---------------------------------------------------------------------------
// XCD-sliced CSR aggregation, edge-parallel waves.
// g is slice-major [8][N][16] (each slice 3.2 MB, L2-resident per XCD).
// Wave = one (node, slice): lanes = 8 edge-groups x 8 channel-pairs ->
// one 64-lane float2 load covers 8 edges x 64 B = 512 B from the hot slice.
// Block = 4 waves = 4 nodes; slice = blockIdx.x & 7 -> XCD.
// out = relu(dis[node] * sum_e g[src[e]] + bias) -> bf16 hi/lo (row-major).
// ---------------------------------------------------------------------------

__global__ __launch_bounds__(256) void aggregate_kernel(const float* __restrict__ gs,
                                                        const int* __restrict__ row_ptr,
                                                        const int* __restrict__ csr_src,
                                                        const float* __restrict__ dis,
                                                        const float* __restrict__ bias,
                                                        ushort* __restrict__ Hi,
                                                        ushort* __restrict__ Lo) {
    const int slice = blockIdx.x & 7;
    const int nb = blockIdx.x >> 3;          // node-group of 4
    const int wid = threadIdx.x >> 6;
    const int lane = threadIdx.x & 63;
    const int eg = lane >> 3;                // edge group 0..7
    const int cp = lane & 7;                 // channel pair 0..7
    const int node = nb * 4 + wid;
    const float* __restrict__ g = gs + (size_t)slice * ((size_t)N_NODES * 16);

    const int s0 = __builtin_nontemporal_load(&row_ptr[node]);
    const int s1 = __builtin_nontemporal_load(&row_ptr[node + 1]);

    float ax = 0.f, ay = 0.f;
    for (int e = s0; e < s1; e += 8) {
        int ee = e + eg;
        bool valid = ee < s1;
        int ec = valid ? ee : (s1 - 1);      // degree >= 1 always (self-loop)
        int idx = __builtin_nontemporal_load(&csr_src[ec]);
        float2 v = *(const float2*)&g[(size_t)idx * 16 + cp * 2];
        if (valid) {
            ax += v.x;
            ay += v.y;
        }
    }
    // Fold the 8 edge-groups (lanes differing in bits 3..5)
    ax += __shfl_xor(ax, 8);
    ay += __shfl_xor(ay, 8);
    ax += __shfl_xor(ax, 16);
    ay += __shfl_xor(ay, 16);
    ax += __shfl_xor(ax, 32);
    ay += __shfl_xor(ay, 32);

    if (eg == 0) {
        const int ch = slice * 16 + cp * 2;
        const float dn = dis[node];
        float vx = fmaxf(dn * ax + bias[ch + 0], 0.f);
        float vy = fmaxf(dn * ay + bias[ch + 1], 0.f);
        ushort hx = f2bf(vx), hy = f2bf(vy);
        ushort lx = f2bf(vx - bf2f(hx)), ly = f2bf(vy - bf2f(hy));
        uint hw = (uint)hx | ((uint)hy << 16);
        uint lw = (uint)lx | ((uint)ly << 16);
        __builtin_nontemporal_store(hw, (uint*)&Hi[(size_t)node * HID_C + ch]);
        __builtin_nontemporal_store(lw, (uint*)&Lo[(size_t)node * HID_C + ch]);
    }
}

// ---------------------------------------------------------------------------
// Launch
// ---------------------------------------------------------------------------

extern "C" void kernel_launch(void* const* d_in, const int* in_sizes, int n_in,
                              void* d_out, int out_size, void* d_ws, size_t ws_size,
                              hipStream_t stream) {
    const float* x       = (const float*)d_in[0];
    const int*   eidx    = (const int*)d_in[1];
    const float* proj_W  = (const float*)d_in[2];
    const float* proj_b  = (const float*)d_in[3];
    const float* conv_W0 = (const float*)d_in[4];
    const float* conv_b0 = (const float*)d_in[5];
    const float* conv_W1 = (const float*)d_in[6];
    const float* conv_b1 = (const float*)d_in[7];
    const float* conv_W2 = (const float*)d_in[8];
    const float* conv_b2 = (const float*)d_in[9];
    const float* out_W   = (const float*)d_in[10];
    const float* out_b   = (const float*)d_in[11];
    float* out = (float*)d_out;

    const int* src = eidx;
    const int* dst = eidx + N_EDGES;

    char* ws = (char*)d_ws;
    size_t off = 0;
    auto carve = [&](size_t bytes) {
        void* p = ws + off;
        off += (bytes + 255) & ~(size_t)255;
        return p;
    };
    int*   degi     = (int*)carve(N_NODES * sizeof(int));
    int*   row_ptr  = (int*)carve((N_NODES + 1) * sizeof(int));
    int*   cursor   = (int*)carve(N_NODES * sizeof(int));
    int*   csr_src  = (int*)carve((size_t)(N_EDGES + N_NODES) * sizeof(int));
    float* dis      = (float*)carve(N_NODES * sizeof(float));
    int*   partials = (int*)carve(NB_SCAN * sizeof(int));
    int*   poff     = (int*)carve(NB_SCAN * sizeof(int));
    ushort* projPh = (ushort*)carve((size_t)IN_C * HID_C * sizeof(ushort));
    ushort* projPl = (ushort*)carve((size_t)IN_C * HID_C * sizeof(ushort));
    ushort* convPh[3], *convPl[3];
    for (int l = 0; l < 3; l++) {
        convPh[l] = (ushort*)carve((size_t)HID_C * HID_C * sizeof(ushort));
        convPl[l] = (ushort*)carve((size_t)HID_C * HID_C * sizeof(ushort));
    }
    ushort* outPh = (ushort*)carve((size_t)HID_C * OUT_C * sizeof(ushort));
    ushort* outPl = (ushort*)carve((size_t)HID_C * OUT_C * sizeof(ushort));
    ushort* hHi = (ushort*)carve((size_t)N_NODES * HID_C * sizeof(ushort));
    ushort* hLo = (ushort*)carve((size_t)N_NODES * HID_C * sizeof(ushort));
    float*  g   = (float*)carve((size_t)N_NODES * HID_C * sizeof(float));  // slice-major

    // Graph preprocessing
    init_deg_kernel<<<NB_SCAN, 256, 0, stream>>>(degi);
    count_deg_kernel<<<(N_EDGES + 255) / 256, 256, 0, stream>>>(dst, degi);
    deg_partial_kernel<<<NB_SCAN, 256, 0, stream>>>(degi, partials);
    scan_partials_kernel<<<1, 256, 0, stream>>>(partials, poff, row_ptr);
    scan_final_kernel<<<NB_SCAN, 256, 0, stream>>>(degi, poff, row_ptr, cursor, dis);
    scatter_kernel<<<(N_EDGES + N_NODES + 255) / 256, 256, 0, stream>>>(
        src, dst, cursor, csr_src);

    // Weight packing
    pack_w_kernel<<<(IN_C / 32) * (HID_C / 16), 64, 0, stream>>>(proj_W, projPh, projPl, IN_C, HID_C);
    pack_w_kernel<<<(HID_C / 32) * (HID_C / 16), 64, 0, stream>>>(conv_W0, convPh[0], convPl[0], HID_C, HID_C);
    pack_w_kernel<<<(HID_C / 32) * (HID_C / 16), 64, 0, stream>>>(conv_W1, convPh[1], convPl[1], HID_C, HID_C);
    pack_w_kernel<<<(HID_C / 32) * (HID_C / 16), 64, 0, stream>>>(conv_W2, convPh[2], convPl[2], HID_C, HID_C);
    pack_w_kernel<<<(HID_C / 32) * (OUT_C / 16), 64, 0, stream>>>(out_W, outPh, outPl, HID_C, OUT_C);

    const int gemm_grid = (N_NODES + 127) / 128;  // 391
    const int agg_grid = (N_NODES / 4) * 8;       // 100000 (4 nodes/block x 8 slices)

    // Projection: h = x @ proj_W + proj_b  -> hi/lo
    gemm_mfma_kernel<IN_C, HID_C, 1, true><<<gemm_grid, 256, 0, stream>>>(
        x, nullptr, nullptr, projPh, projPl, proj_b, nullptr, nullptr, hHi, hLo, N_NODES);

    // 3 GCN layers
    ushort* Wh_[3] = {convPh[0], convPh[1], convPh[2]};
    ushort* Wl_[3] = {convPl[0], convPl[1], convPl[2]};
    const float* bs_[3] = {conv_b0, conv_b1, conv_b2};
    for (int l = 0; l < 3; l++) {
        // g[slice][node][16] = dis[node] * (h @ W)[node]
        gemm_mfma_kernel<HID_C, HID_C, 2, false><<<gemm_grid, 256, 0, stream>>>(
            nullptr, hHi, hLo, Wh_[l], Wl_[l], nullptr, dis, g, nullptr, nullptr, N_NODES);
        aggregate_kernel<<<agg_grid, 256, 0, stream>>>(
            g, row_ptr, csr_src, dis, bs_[l], hHi, hLo);
    }

    // Output: out = h @ out_W + out_b (fp32)
    gemm_mfma_kernel<HID_C, OUT_C, 0, false><<<gemm_grid, 256, 0, stream>>>(
        nullptr, hHi, hLo, outPh, outPl, out_b, nullptr, out, nullptr, nullptr, N_NODES);
}

// Round 6
// 407.466 us; speedup vs baseline: 1.9094x; 1.9094x over previous
//
#include <hip/hip_runtime.h>
#include <hip/hip_bf16.h>

// Problem constants (match reference)
#define N_NODES 50000
#define N_EDGES 800000
#define IN_C 256
#define HID_C 128
#define OUT_C 64

#define NB_SCAN ((N_NODES + 255) / 256)   // 196 blocks of 256 nodes

typedef __attribute__((ext_vector_type(8))) short bf16x8;
typedef __attribute__((ext_vector_type(4))) float f32x4;

__device__ __forceinline__ ushort f2bf(float f) {
    uint u = __float_as_uint(f);
    u += 0x7fff + ((u >> 16) & 1);   // round-to-nearest-even
    return (ushort)(u >> 16);
}
__device__ __forceinline__ float bf2f(ushort h) {
    return __uint_as_float(((uint)h) << 16);
}

// ---------------------------------------------------------------------------
// Graph preprocessing
// ---------------------------------------------------------------------------

__global__ __launch_bounds__(256) void init_deg_kernel(int* __restrict__ degi) {
    int i = blockIdx.x * 256 + threadIdx.x;
    if (i < N_NODES) degi[i] = 1;  // self-loop
}

__global__ __launch_bounds__(256) void count_deg_kernel(const int* __restrict__ dst,
                                                        int* __restrict__ degi) {
    int e = blockIdx.x * 256 + threadIdx.x;
    if (e < N_EDGES) atomicAdd(&degi[dst[e]], 1);
}

__global__ __launch_bounds__(256) void deg_partial_kernel(const int* __restrict__ degi,
                                                          int* __restrict__ partials) {
    __shared__ int s[256];
    int t = threadIdx.x;
    int i = blockIdx.x * 256 + t;
    s[t] = (i < N_NODES) ? degi[i] : 0;
    __syncthreads();
#pragma unroll
    for (int off = 128; off > 0; off >>= 1) {
        if (t < off) s[t] += s[t + off];
        __syncthreads();
    }
    if (t == 0) partials[blockIdx.x] = s[0];
}

__global__ __launch_bounds__(256) void scan_partials_kernel(const int* __restrict__ partials,
                                                            int* __restrict__ partial_off,
                                                            int* __restrict__ row_ptr) {
    __shared__ int s[256];
    int t = threadIdx.x;
    s[t] = (t < NB_SCAN) ? partials[t] : 0;
    __syncthreads();
#pragma unroll
    for (int off = 1; off < 256; off <<= 1) {
        int x = s[t];
        int add = (t >= off) ? s[t - off] : 0;
        __syncthreads();
        s[t] = x + add;
        __syncthreads();
    }
    if (t < NB_SCAN) partial_off[t] = (t == 0) ? 0 : s[t - 1];
    if (t == 255) row_ptr[N_NODES] = s[255];
}

__global__ __launch_bounds__(256) void scan_final_kernel(const int* __restrict__ degi,
                                                         const int* __restrict__ partial_off,
                                                         int* __restrict__ row_ptr,
                                                         int* __restrict__ cursor,
                                                         float* __restrict__ dis) {
    __shared__ int s[256];
    int t = threadIdx.x;
    int i = blockIdx.x * 256 + t;
    int d = (i < N_NODES) ? degi[i] : 0;
    s[t] = d;
    __syncthreads();
#pragma unroll
    for (int off = 1; off < 256; off <<= 1) {
        int x = s[t];
        int add = (t >= off) ? s[t - off] : 0;
        __syncthreads();
        s[t] = x + add;
        __syncthreads();
    }
    if (i < N_NODES) {
        int excl = partial_off[blockIdx.x] + s[t] - d;
        row_ptr[i] = excl;
        cursor[i] = excl;
        dis[i] = rsqrtf((float)d);
    }
}

// 4B scatter per edge: src index only (norm is factorized via dis)
__global__ __launch_bounds__(256) void scatter_kernel(const int* __restrict__ src,
                                                      const int* __restrict__ dst,
                                                      int* __restrict__ cursor,
                                                      int* __restrict__ csr_src) {
    int i = blockIdx.x * 256 + threadIdx.x;
    if (i >= N_EDGES + N_NODES) return;
    int s, d;
    if (i < N_EDGES) {
        s = src[i];
        d = dst[i];
    } else {
        s = d = i - N_EDGES;
    }
    int slot = atomicAdd(&cursor[d], 1);
    csr_src[slot] = s;
}

// ---------------------------------------------------------------------------
// Weight packing: W[K][N] fp32 -> fragment-ordered bf16 hi/lo
// layout: Pk[kt][ct][lane][j], element = W[kt*32 + (lane>>4)*8 + j][ct*16 + (lane&15)]
// ---------------------------------------------------------------------------

__global__ __launch_bounds__(64) void pack_w_kernel(const float* __restrict__ W,
                                                    ushort* __restrict__ Ph,
                                                    ushort* __restrict__ Pl,
                                                    int K, int N) {
    int lane = threadIdx.x;
    int CT = N / 16;
    int ct = blockIdx.x % CT;
    int kt = blockIdx.x / CT;
    int lr = lane & 15, lg = lane >> 4;
    size_t base = ((size_t)blockIdx.x * 64 + lane) * 8;
#pragma unroll
    for (int j = 0; j < 8; j++) {
        float w = W[(size_t)(kt * 32 + lg * 8 + j) * N + ct * 16 + lr];
        ushort h = f2bf(w);
        ushort lo = f2bf(w - bf2f(h));
        Ph[base + j] = h;
        Pl[base + j] = lo;
    }
}

// ---------------------------------------------------------------------------
// LDS-free MFMA GEMM with 3-term bf16 split.
// C[M][N] = A[M][K] @ W[K][N]. Wave owns 32 rows x N cols; block = 128 rows.
// OUT_MODE: 0 = fp32 + bias (row-major), 1 = bf16 hi/lo + bias (row-major),
//           2 = fp32 * dis[row] (row-major, no bias)
// ---------------------------------------------------------------------------

template <int K, int N, int OUT_MODE, bool AF32>
__global__ __launch_bounds__(256) void gemm_mfma_kernel(
    const float* __restrict__ Af, const ushort* __restrict__ Ahi,
    const ushort* __restrict__ Alo, const ushort* __restrict__ Wph,
    const ushort* __restrict__ Wpl, const float* __restrict__ bias,
    const float* __restrict__ disp, float* __restrict__ Cf,
    ushort* __restrict__ CHi, ushort* __restrict__ CLo, int M) {
    constexpr int CT = N / 16;
    constexpr int KT = K / 32;

    const int wid = threadIdx.x >> 6;
    const int lane = threadIdx.x & 63;
    const int lr = lane & 15;
    const int lg = lane >> 4;
    const int row_base = blockIdx.x * 128 + wid * 32;

    f32x4 acc[2][CT];
#pragma unroll
    for (int rt = 0; rt < 2; rt++)
#pragma unroll
        for (int ct = 0; ct < CT; ct++) acc[rt][ct] = (f32x4){0.f, 0.f, 0.f, 0.f};

    for (int kt = 0; kt < KT; kt++) {
        const int kof = kt * 32 + lg * 8;
        bf16x8 ah[2], al[2];
#pragma unroll
        for (int rt = 0; rt < 2; rt++) {
            int r = row_base + rt * 16 + lr;
            if (r >= M) r = M - 1;  // clamp; result discarded on store
            if (AF32) {
                const float* ap = &Af[(size_t)r * K + kof];
                float4 v0 = *(const float4*)ap;
                float4 v1 = *(const float4*)(ap + 4);
                float av[8] = {v0.x, v0.y, v0.z, v0.w, v1.x, v1.y, v1.z, v1.w};
#pragma unroll
                for (int j = 0; j < 8; j++) {
                    ushort h = f2bf(av[j]);
                    ushort lo = f2bf(av[j] - bf2f(h));
                    ah[rt][j] = (short)h;
                    al[rt][j] = (short)lo;
                }
            } else {
                ah[rt] = *(const bf16x8*)&Ahi[(size_t)r * K + kof];
                al[rt] = *(const bf16x8*)&Alo[(size_t)r * K + kof];
            }
        }
        const ushort* bh = &Wph[(size_t)kt * CT * 512 + (size_t)lane * 8];
        const ushort* bl = &Wpl[(size_t)kt * CT * 512 + (size_t)lane * 8];
#pragma unroll
        for (int ct = 0; ct < CT; ct++) {
            bf16x8 bhv = *(const bf16x8*)(bh + ct * 512);
            bf16x8 blv = *(const bf16x8*)(bl + ct * 512);
#pragma unroll
            for (int rt = 0; rt < 2; rt++) {
                acc[rt][ct] = __builtin_amdgcn_mfma_f32_16x16x32_bf16(ah[rt], bhv, acc[rt][ct], 0, 0, 0);
                acc[rt][ct] = __builtin_amdgcn_mfma_f32_16x16x32_bf16(al[rt], bhv, acc[rt][ct], 0, 0, 0);
                acc[rt][ct] = __builtin_amdgcn_mfma_f32_16x16x32_bf16(ah[rt], blv, acc[rt][ct], 0, 0, 0);
            }
        }
    }

    // Epilogue: D[row][col], row = rt*16 + lg*4 + j, col = ct*16 + lr
#pragma unroll
    for (int rt = 0; rt < 2; rt++)
#pragma unroll
        for (int ct = 0; ct < CT; ct++)
#pragma unroll
            for (int j = 0; j < 4; j++) {
                int r = row_base + rt * 16 + lg * 4 + j;
                if (r >= M) continue;
                int c = ct * 16 + lr;
                float v = acc[rt][ct][j];
                if (OUT_MODE == 2) {
                    Cf[(size_t)r * N + c] = v * disp[r];
                } else {
                    v += bias[c];
                    if (OUT_MODE == 1) {
                        ushort h = f2bf(v);
                        ushort lo = f2bf(v - bf2f(h));
                        CHi[(size_t)r * N + c] = h;
                        CLo[(size_t)r * N + c] = lo;
                    } else {
                        Cf[(size_t)r * N + c] = v;
                    }
                }
            }
}

// ---------------------------------------------------------------------------
// CSR aggregation: wave = node, 64 lanes x float2 = full 128-ch row per
// instruction. Edge loop unrolled x8: one broadcast index read feeds 8
// independent 512B row-gathers (deep MLP). g row-major fp32, pre-scaled by
// dis[src] in the GEMM epilogue.
// out = relu(dis[node] * sum + bias) -> bf16 hi/lo (row-major).
// ---------------------------------------------------------------------------

__global__ __launch_bounds__(256) void aggregate_kernel(const float* __restrict__ g,
                                                        const int* __restrict__ row_ptr,
                                                        const int* __restrict__ csr_src,
                                                        const float* __restrict__ dis,
                                                        const float* __restrict__ bias,
                                                        ushort* __restrict__ Hi,
                                                        ushort* __restrict__ Lo) {
    const int wid = threadIdx.x >> 6;
    const int lane = threadIdx.x & 63;
    const int node = blockIdx.x * 4 + wid;
    if (node >= N_NODES) return;
    const int c2 = lane * 2;

    const int s0 = row_ptr[node];
    const int s1 = row_ptr[node + 1];

    float ax = 0.f, ay = 0.f;
    int e = s0;
    for (; e + 8 <= s1; e += 8) {
        int i0 = csr_src[e + 0];
        int i1 = csr_src[e + 1];
        int i2 = csr_src[e + 2];
        int i3 = csr_src[e + 3];
        int i4 = csr_src[e + 4];
        int i5 = csr_src[e + 5];
        int i6 = csr_src[e + 6];
        int i7 = csr_src[e + 7];
        float2 v0 = *(const float2*)&g[(size_t)i0 * HID_C + c2];
        float2 v1 = *(const float2*)&g[(size_t)i1 * HID_C + c2];
        float2 v2 = *(const float2*)&g[(size_t)i2 * HID_C + c2];
        float2 v3 = *(const float2*)&g[(size_t)i3 * HID_C + c2];
        float2 v4 = *(const float2*)&g[(size_t)i4 * HID_C + c2];
        float2 v5 = *(const float2*)&g[(size_t)i5 * HID_C + c2];
        float2 v6 = *(const float2*)&g[(size_t)i6 * HID_C + c2];
        float2 v7 = *(const float2*)&g[(size_t)i7 * HID_C + c2];
        ax += ((v0.x + v1.x) + (v2.x + v3.x)) + ((v4.x + v5.x) + (v6.x + v7.x));
        ay += ((v0.y + v1.y) + (v2.y + v3.y)) + ((v4.y + v5.y) + (v6.y + v7.y));
    }
    for (; e < s1; e++) {
        int i0 = csr_src[e];
        float2 v0 = *(const float2*)&g[(size_t)i0 * HID_C + c2];
        ax += v0.x;
        ay += v0.y;
    }

    const float dn = dis[node];
    float2 bb = *(const float2*)&bias[c2];
    float vx = fmaxf(dn * ax + bb.x, 0.f);
    float vy = fmaxf(dn * ay + bb.y, 0.f);
    ushort hx = f2bf(vx), hy = f2bf(vy);
    ushort lx = f2bf(vx - bf2f(hx)), ly = f2bf(vy - bf2f(hy));
    uint hw = (uint)hx | ((uint)hy << 16);
    uint lw = (uint)lx | ((uint)ly << 16);
    *(uint*)&Hi[(size_t)node * HID_C + c2] = hw;
    *(uint*)&Lo[(size_t)node * HID_C + c2] = lw;
}

// ---------------------------------------------------------------------------
// Launch
// ---------------------------------------------------------------------------

extern "C" void kernel_launch(void* const* d_in, const int* in_sizes, int n_in,
                              void* d_out, int out_size, void* d_ws, size_t ws_size,
                              hipStream_t stream) {
    const float* x       = (const float*)d_in[0];
    const int*   eidx    = (const int*)d_in[1];
    const float* proj_W  = (const float*)d_in[2];
    const float* proj_b  = (const float*)d_in[3];
    const float* conv_W0 = (const float*)d_in[4];
    const float* conv_b0 = (const float*)d_in[5];
    const float* conv_W1 = (const float*)d_in[6];
    const float* conv_b1 = (const float*)d_in[7];
    const float* conv_W2 = (const float*)d_in[8];
    const float* conv_b2 = (const float*)d_in[9];
    const float* out_W   = (const float*)d_in[10];
    const float* out_b   = (const float*)d_in[11];
    float* out = (float*)d_out;

    const int* src = eidx;
    const int* dst = eidx + N_EDGES;

    char* ws = (char*)d_ws;
    size_t off = 0;
    auto carve = [&](size_t bytes) {
        void* p = ws + off;
        off += (bytes + 255) & ~(size_t)255;
        return p;
    };
    int*   degi     = (int*)carve(N_NODES * sizeof(int));
    int*   row_ptr  = (int*)carve((N_NODES + 1) * sizeof(int));
    int*   cursor   = (int*)carve(N_NODES * sizeof(int));
    int*   csr_src  = (int*)carve((size_t)(N_EDGES + N_NODES) * sizeof(int));
    float* dis      = (float*)carve(N_NODES * sizeof(float));
    int*   partials = (int*)carve(NB_SCAN * sizeof(int));
    int*   poff     = (int*)carve(NB_SCAN * sizeof(int));
    ushort* projPh = (ushort*)carve((size_t)IN_C * HID_C * sizeof(ushort));
    ushort* projPl = (ushort*)carve((size_t)IN_C * HID_C * sizeof(ushort));
    ushort* convPh[3], *convPl[3];
    for (int l = 0; l < 3; l++) {
        convPh[l] = (ushort*)carve((size_t)HID_C * HID_C * sizeof(ushort));
        convPl[l] = (ushort*)carve((size_t)HID_C * HID_C * sizeof(ushort));
    }
    ushort* outPh = (ushort*)carve((size_t)HID_C * OUT_C * sizeof(ushort));
    ushort* outPl = (ushort*)carve((size_t)HID_C * OUT_C * sizeof(ushort));
    ushort* hHi = (ushort*)carve((size_t)N_NODES * HID_C * sizeof(ushort));
    ushort* hLo = (ushort*)carve((size_t)N_NODES * HID_C * sizeof(ushort));
    float*  g   = (float*)carve((size_t)N_NODES * HID_C * sizeof(float));  // row-major

    // Graph preprocessing
    init_deg_kernel<<<NB_SCAN, 256, 0, stream>>>(degi);
    count_deg_kernel<<<(N_EDGES + 255) / 256, 256, 0, stream>>>(dst, degi);
    deg_partial_kernel<<<NB_SCAN, 256, 0, stream>>>(degi, partials);
    scan_partials_kernel<<<1, 256, 0, stream>>>(partials, poff, row_ptr);
    scan_final_kernel<<<NB_SCAN, 256, 0, stream>>>(degi, poff, row_ptr, cursor, dis);
    scatter_kernel<<<(N_EDGES + N_NODES + 255) / 256, 256, 0, stream>>>(
        src, dst, cursor, csr_src);

    // Weight packing
    pack_w_kernel<<<(IN_C / 32) * (HID_C / 16), 64, 0, stream>>>(proj_W, projPh, projPl, IN_C, HID_C);
    pack_w_kernel<<<(HID_C / 32) * (HID_C / 16), 64, 0, stream>>>(conv_W0, convPh[0], convPl[0], HID_C, HID_C);
    pack_w_kernel<<<(HID_C / 32) * (HID_C / 16), 64, 0, stream>>>(conv_W1, convPh[1], convPl[1], HID_C, HID_C);
    pack_w_kernel<<<(HID_C / 32) * (HID_C / 16), 64, 0, stream>>>(conv_W2, convPh[2], convPl[2], HID_C, HID_C);
    pack_w_kernel<<<(HID_C / 32) * (OUT_C / 16), 64, 0, stream>>>(out_W, outPh, outPl, HID_C, OUT_C);

    const int gemm_grid = (N_NODES + 127) / 128;  // 391
    const int agg_grid = (N_NODES + 3) / 4;       // 12500

    // Projection: h = x @ proj_W + proj_b  -> hi/lo
    gemm_mfma_kernel<IN_C, HID_C, 1, true><<<gemm_grid, 256, 0, stream>>>(
        x, nullptr, nullptr, projPh, projPl, proj_b, nullptr, nullptr, hHi, hLo, N_NODES);

    // 3 GCN layers
    ushort* Wh_[3] = {convPh[0], convPh[1], convPh[2]};
    ushort* Wl_[3] = {convPl[0], convPl[1], convPl[2]};
    const float* bs_[3] = {conv_b0, conv_b1, conv_b2};
    for (int l = 0; l < 3; l++) {
        // g[node][128] = dis[node] * (h @ W)[node]
        gemm_mfma_kernel<HID_C, HID_C, 2, false><<<gemm_grid, 256, 0, stream>>>(
            nullptr, hHi, hLo, Wh_[l], Wl_[l], nullptr, dis, g, nullptr, nullptr, N_NODES);
        aggregate_kernel<<<agg_grid, 256, 0, stream>>>(
            g, row_ptr, csr_src, dis, bs_[l], hHi, hLo);
    }

    // Output: out = h @ out_W + out_b (fp32)
    gemm_mfma_kernel<HID_C, OUT_C, 0, false><<<gemm_grid, 256, 0, stream>>>(
        nullptr, hHi, hLo, outPh, outPl, out_b, nullptr, out, nullptr, nullptr, N_NODES);
}

// Round 7
// 349.589 us; speedup vs baseline: 2.2255x; 1.1656x over previous
//
#include <hip/hip_runtime.h>
#include <hip/hip_bf16.h>

// Problem constants (match reference)
#define N_NODES 50000
#define N_EDGES 800000
#define IN_C 256
#define HID_C 128
#define OUT_C 64

#define NB_SCAN ((N_NODES + 255) / 256)   // 196 blocks of 256 nodes

typedef __attribute__((ext_vector_type(8))) short bf16x8;
typedef __attribute__((ext_vector_type(4))) float f32x4;
typedef __attribute__((ext_vector_type(2))) _Float16 f16x2;

__device__ __forceinline__ ushort f2bf(float f) {
    uint u = __float_as_uint(f);
    u += 0x7fff + ((u >> 16) & 1);   // round-to-nearest-even
    return (ushort)(u >> 16);
}
__device__ __forceinline__ float bf2f(ushort h) {
    return __uint_as_float(((uint)h) << 16);
}

// ---------------------------------------------------------------------------
// Graph preprocessing
// ---------------------------------------------------------------------------

__global__ __launch_bounds__(256) void init_deg_kernel(int* __restrict__ degi) {
    int i = blockIdx.x * 256 + threadIdx.x;
    if (i < N_NODES) degi[i] = 1;  // self-loop
}

__global__ __launch_bounds__(256) void count_deg_kernel(const int* __restrict__ dst,
                                                        int* __restrict__ degi) {
    int e = blockIdx.x * 256 + threadIdx.x;
    if (e < N_EDGES) atomicAdd(&degi[dst[e]], 1);
}

__global__ __launch_bounds__(256) void deg_partial_kernel(const int* __restrict__ degi,
                                                          int* __restrict__ partials) {
    __shared__ int s[256];
    int t = threadIdx.x;
    int i = blockIdx.x * 256 + t;
    s[t] = (i < N_NODES) ? degi[i] : 0;
    __syncthreads();
#pragma unroll
    for (int off = 128; off > 0; off >>= 1) {
        if (t < off) s[t] += s[t + off];
        __syncthreads();
    }
    if (t == 0) partials[blockIdx.x] = s[0];
}

__global__ __launch_bounds__(256) void scan_partials_kernel(const int* __restrict__ partials,
                                                            int* __restrict__ partial_off,
                                                            int* __restrict__ row_ptr) {
    __shared__ int s[256];
    int t = threadIdx.x;
    s[t] = (t < NB_SCAN) ? partials[t] : 0;
    __syncthreads();
#pragma unroll
    for (int off = 1; off < 256; off <<= 1) {
        int x = s[t];
        int add = (t >= off) ? s[t - off] : 0;
        __syncthreads();
        s[t] = x + add;
        __syncthreads();
    }
    if (t < NB_SCAN) partial_off[t] = (t == 0) ? 0 : s[t - 1];
    if (t == 255) row_ptr[N_NODES] = s[255];
}

__global__ __launch_bounds__(256) void scan_final_kernel(const int* __restrict__ degi,
                                                         const int* __restrict__ partial_off,
                                                         int* __restrict__ row_ptr,
                                                         int* __restrict__ cursor,
                                                         float* __restrict__ dis) {
    __shared__ int s[256];
    int t = threadIdx.x;
    int i = blockIdx.x * 256 + t;
    int d = (i < N_NODES) ? degi[i] : 0;
    s[t] = d;
    __syncthreads();
#pragma unroll
    for (int off = 1; off < 256; off <<= 1) {
        int x = s[t];
        int add = (t >= off) ? s[t - off] : 0;
        __syncthreads();
        s[t] = x + add;
        __syncthreads();
    }
    if (i < N_NODES) {
        int excl = partial_off[blockIdx.x] + s[t] - d;
        row_ptr[i] = excl;
        cursor[i] = excl;
        dis[i] = rsqrtf((float)d);
    }
}

// 4B scatter per edge: src index only (norm is factorized via dis)
__global__ __launch_bounds__(256) void scatter_kernel(const int* __restrict__ src,
                                                      const int* __restrict__ dst,
                                                      int* __restrict__ cursor,
                                                      int* __restrict__ csr_src) {
    int i = blockIdx.x * 256 + threadIdx.x;
    if (i >= N_EDGES + N_NODES) return;
    int s, d;
    if (i < N_EDGES) {
        s = src[i];
        d = dst[i];
    } else {
        s = d = i - N_EDGES;
    }
    int slot = atomicAdd(&cursor[d], 1);
    csr_src[slot] = s;
}

// ---------------------------------------------------------------------------
// Weight packing: W[K][N] fp32 -> fragment-ordered bf16 hi/lo
// layout: Pk[kt][ct][lane][j], element = W[kt*32 + (lane>>4)*8 + j][ct*16 + (lane&15)]
// ---------------------------------------------------------------------------

__global__ __launch_bounds__(64) void pack_w_kernel(const float* __restrict__ W,
                                                    ushort* __restrict__ Ph,
                                                    ushort* __restrict__ Pl,
                                                    int K, int N) {
    int lane = threadIdx.x;
    int CT = N / 16;
    int ct = blockIdx.x % CT;
    int kt = blockIdx.x / CT;
    int lr = lane & 15, lg = lane >> 4;
    size_t base = ((size_t)blockIdx.x * 64 + lane) * 8;
#pragma unroll
    for (int j = 0; j < 8; j++) {
        float w = W[(size_t)(kt * 32 + lg * 8 + j) * N + ct * 16 + lr];
        ushort h = f2bf(w);
        ushort lo = f2bf(w - bf2f(h));
        Ph[base + j] = h;
        Pl[base + j] = lo;
    }
}

// ---------------------------------------------------------------------------
// LDS-free MFMA GEMM with 3-term bf16 split.
// C[M][N] = A[M][K] @ W[K][N]. Wave owns 32 rows x N cols; block = 128 rows.
// OUT_MODE: 0 = fp32 + bias (row-major), 1 = bf16 hi/lo + bias (row-major),
//           2 = fp16 * dis[row] (row-major, no bias)
// ---------------------------------------------------------------------------

template <int K, int N, int OUT_MODE, bool AF32>
__global__ __launch_bounds__(256) void gemm_mfma_kernel(
    const float* __restrict__ Af, const ushort* __restrict__ Ahi,
    const ushort* __restrict__ Alo, const ushort* __restrict__ Wph,
    const ushort* __restrict__ Wpl, const float* __restrict__ bias,
    const float* __restrict__ disp, float* __restrict__ Cf,
    ushort* __restrict__ CHi, ushort* __restrict__ CLo, int M) {
    constexpr int CT = N / 16;
    constexpr int KT = K / 32;

    const int wid = threadIdx.x >> 6;
    const int lane = threadIdx.x & 63;
    const int lr = lane & 15;
    const int lg = lane >> 4;
    const int row_base = blockIdx.x * 128 + wid * 32;

    f32x4 acc[2][CT];
#pragma unroll
    for (int rt = 0; rt < 2; rt++)
#pragma unroll
        for (int ct = 0; ct < CT; ct++) acc[rt][ct] = (f32x4){0.f, 0.f, 0.f, 0.f};

    for (int kt = 0; kt < KT; kt++) {
        const int kof = kt * 32 + lg * 8;
        bf16x8 ah[2], al[2];
#pragma unroll
        for (int rt = 0; rt < 2; rt++) {
            int r = row_base + rt * 16 + lr;
            if (r >= M) r = M - 1;  // clamp; result discarded on store
            if (AF32) {
                const float* ap = &Af[(size_t)r * K + kof];
                float4 v0 = *(const float4*)ap;
                float4 v1 = *(const float4*)(ap + 4);
                float av[8] = {v0.x, v0.y, v0.z, v0.w, v1.x, v1.y, v1.z, v1.w};
#pragma unroll
                for (int j = 0; j < 8; j++) {
                    ushort h = f2bf(av[j]);
                    ushort lo = f2bf(av[j] - bf2f(h));
                    ah[rt][j] = (short)h;
                    al[rt][j] = (short)lo;
                }
            } else {
                ah[rt] = *(const bf16x8*)&Ahi[(size_t)r * K + kof];
                al[rt] = *(const bf16x8*)&Alo[(size_t)r * K + kof];
            }
        }
        const ushort* bh = &Wph[(size_t)kt * CT * 512 + (size_t)lane * 8];
        const ushort* bl = &Wpl[(size_t)kt * CT * 512 + (size_t)lane * 8];
#pragma unroll
        for (int ct = 0; ct < CT; ct++) {
            bf16x8 bhv = *(const bf16x8*)(bh + ct * 512);
            bf16x8 blv = *(const bf16x8*)(bl + ct * 512);
#pragma unroll
            for (int rt = 0; rt < 2; rt++) {
                acc[rt][ct] = __builtin_amdgcn_mfma_f32_16x16x32_bf16(ah[rt], bhv, acc[rt][ct], 0, 0, 0);
                acc[rt][ct] = __builtin_amdgcn_mfma_f32_16x16x32_bf16(al[rt], bhv, acc[rt][ct], 0, 0, 0);
                acc[rt][ct] = __builtin_amdgcn_mfma_f32_16x16x32_bf16(ah[rt], blv, acc[rt][ct], 0, 0, 0);
            }
        }
    }

    // Epilogue: D[row][col], row = rt*16 + lg*4 + j, col = ct*16 + lr
#pragma unroll
    for (int rt = 0; rt < 2; rt++)
#pragma unroll
        for (int ct = 0; ct < CT; ct++)
#pragma unroll
            for (int j = 0; j < 4; j++) {
                int r = row_base + rt * 16 + lg * 4 + j;
                if (r >= M) continue;
                int c = ct * 16 + lr;
                float v = acc[rt][ct][j];
                if (OUT_MODE == 2) {
                    // fp16 g, pre-scaled by dis[row]
                    _Float16* Ch = (_Float16*)Cf;
                    Ch[(size_t)r * N + c] = (_Float16)(v * disp[r]);
                } else {
                    v += bias[c];
                    if (OUT_MODE == 1) {
                        ushort h = f2bf(v);
                        ushort lo = f2bf(v - bf2f(h));
                        CHi[(size_t)r * N + c] = h;
                        CLo[(size_t)r * N + c] = lo;
                    } else {
                        Cf[(size_t)r * N + c] = v;
                    }
                }
            }
}

// ---------------------------------------------------------------------------
// CSR aggregation: wave = node, 64 lanes x half2 = full 128-ch fp16 row
// (256 B) per instruction. Edge loop unrolled x8 for MLP. g pre-scaled by
// dis[src] in the GEMM epilogue.
// out = relu(dis[node] * sum + bias) -> bf16 hi/lo (row-major).
// ---------------------------------------------------------------------------

__global__ __launch_bounds__(256) void aggregate_kernel(const _Float16* __restrict__ g,
                                                        const int* __restrict__ row_ptr,
                                                        const int* __restrict__ csr_src,
                                                        const float* __restrict__ dis,
                                                        const float* __restrict__ bias,
                                                        ushort* __restrict__ Hi,
                                                        ushort* __restrict__ Lo) {
    const int wid = threadIdx.x >> 6;
    const int lane = threadIdx.x & 63;
    const int node = blockIdx.x * 4 + wid;
    if (node >= N_NODES) return;
    const int c2 = lane * 2;

    const int s0 = row_ptr[node];
    const int s1 = row_ptr[node + 1];

    float ax = 0.f, ay = 0.f;
    int e = s0;
    for (; e + 8 <= s1; e += 8) {
        int i0 = csr_src[e + 0];
        int i1 = csr_src[e + 1];
        int i2 = csr_src[e + 2];
        int i3 = csr_src[e + 3];
        int i4 = csr_src[e + 4];
        int i5 = csr_src[e + 5];
        int i6 = csr_src[e + 6];
        int i7 = csr_src[e + 7];
        f16x2 v0 = *(const f16x2*)&g[(size_t)i0 * HID_C + c2];
        f16x2 v1 = *(const f16x2*)&g[(size_t)i1 * HID_C + c2];
        f16x2 v2 = *(const f16x2*)&g[(size_t)i2 * HID_C + c2];
        f16x2 v3 = *(const f16x2*)&g[(size_t)i3 * HID_C + c2];
        f16x2 v4 = *(const f16x2*)&g[(size_t)i4 * HID_C + c2];
        f16x2 v5 = *(const f16x2*)&g[(size_t)i5 * HID_C + c2];
        f16x2 v6 = *(const f16x2*)&g[(size_t)i6 * HID_C + c2];
        f16x2 v7 = *(const f16x2*)&g[(size_t)i7 * HID_C + c2];
        ax += (((float)v0.x + (float)v1.x) + ((float)v2.x + (float)v3.x)) +
              (((float)v4.x + (float)v5.x) + ((float)v6.x + (float)v7.x));
        ay += (((float)v0.y + (float)v1.y) + ((float)v2.y + (float)v3.y)) +
              (((float)v4.y + (float)v5.y) + ((float)v6.y + (float)v7.y));
    }
    for (; e < s1; e++) {
        int i0 = csr_src[e];
        f16x2 v0 = *(const f16x2*)&g[(size_t)i0 * HID_C + c2];
        ax += (float)v0.x;
        ay += (float)v0.y;
    }

    const float dn = dis[node];
    float2 bb = *(const float2*)&bias[c2];
    float vx = fmaxf(dn * ax + bb.x, 0.f);
    float vy = fmaxf(dn * ay + bb.y, 0.f);
    ushort hx = f2bf(vx), hy = f2bf(vy);
    ushort lx = f2bf(vx - bf2f(hx)), ly = f2bf(vy - bf2f(hy));
    uint hw = (uint)hx | ((uint)hy << 16);
    uint lw = (uint)lx | ((uint)ly << 16);
    *(uint*)&Hi[(size_t)node * HID_C + c2] = hw;
    *(uint*)&Lo[(size_t)node * HID_C + c2] = lw;
}

// ---------------------------------------------------------------------------
// Launch
// ---------------------------------------------------------------------------

extern "C" void kernel_launch(void* const* d_in, const int* in_sizes, int n_in,
                              void* d_out, int out_size, void* d_ws, size_t ws_size,
                              hipStream_t stream) {
    const float* x       = (const float*)d_in[0];
    const int*   eidx    = (const int*)d_in[1];
    const float* proj_W  = (const float*)d_in[2];
    const float* proj_b  = (const float*)d_in[3];
    const float* conv_W0 = (const float*)d_in[4];
    const float* conv_b0 = (const float*)d_in[5];
    const float* conv_W1 = (const float*)d_in[6];
    const float* conv_b1 = (const float*)d_in[7];
    const float* conv_W2 = (const float*)d_in[8];
    const float* conv_b2 = (const float*)d_in[9];
    const float* out_W   = (const float*)d_in[10];
    const float* out_b   = (const float*)d_in[11];
    float* out = (float*)d_out;

    const int* src = eidx;
    const int* dst = eidx + N_EDGES;

    char* ws = (char*)d_ws;
    size_t off = 0;
    auto carve = [&](size_t bytes) {
        void* p = ws + off;
        off += (bytes + 255) & ~(size_t)255;
        return p;
    };
    int*   degi     = (int*)carve(N_NODES * sizeof(int));
    int*   row_ptr  = (int*)carve((N_NODES + 1) * sizeof(int));
    int*   cursor   = (int*)carve(N_NODES * sizeof(int));
    int*   csr_src  = (int*)carve((size_t)(N_EDGES + N_NODES) * sizeof(int));
    float* dis      = (float*)carve(N_NODES * sizeof(float));
    int*   partials = (int*)carve(NB_SCAN * sizeof(int));
    int*   poff     = (int*)carve(NB_SCAN * sizeof(int));
    ushort* projPh = (ushort*)carve((size_t)IN_C * HID_C * sizeof(ushort));
    ushort* projPl = (ushort*)carve((size_t)IN_C * HID_C * sizeof(ushort));
    ushort* convPh[3], *convPl[3];
    for (int l = 0; l < 3; l++) {
        convPh[l] = (ushort*)carve((size_t)HID_C * HID_C * sizeof(ushort));
        convPl[l] = (ushort*)carve((size_t)HID_C * HID_C * sizeof(ushort));
    }
    ushort* outPh = (ushort*)carve((size_t)HID_C * OUT_C * sizeof(ushort));
    ushort* outPl = (ushort*)carve((size_t)HID_C * OUT_C * sizeof(ushort));
    ushort* hHi = (ushort*)carve((size_t)N_NODES * HID_C * sizeof(ushort));
    ushort* hLo = (ushort*)carve((size_t)N_NODES * HID_C * sizeof(ushort));
    _Float16* g = (_Float16*)carve((size_t)N_NODES * HID_C * sizeof(_Float16));  // fp16 row-major

    // Graph preprocessing
    init_deg_kernel<<<NB_SCAN, 256, 0, stream>>>(degi);
    count_deg_kernel<<<(N_EDGES + 255) / 256, 256, 0, stream>>>(dst, degi);
    deg_partial_kernel<<<NB_SCAN, 256, 0, stream>>>(degi, partials);
    scan_partials_kernel<<<1, 256, 0, stream>>>(partials, poff, row_ptr);
    scan_final_kernel<<<NB_SCAN, 256, 0, stream>>>(degi, poff, row_ptr, cursor, dis);
    scatter_kernel<<<(N_EDGES + N_NODES + 255) / 256, 256, 0, stream>>>(
        src, dst, cursor, csr_src);

    // Weight packing
    pack_w_kernel<<<(IN_C / 32) * (HID_C / 16), 64, 0, stream>>>(proj_W, projPh, projPl, IN_C, HID_C);
    pack_w_kernel<<<(HID_C / 32) * (HID_C / 16), 64, 0, stream>>>(conv_W0, convPh[0], convPl[0], HID_C, HID_C);
    pack_w_kernel<<<(HID_C / 32) * (HID_C / 16), 64, 0, stream>>>(conv_W1, convPh[1], convPl[1], HID_C, HID_C);
    pack_w_kernel<<<(HID_C / 32) * (HID_C / 16), 64, 0, stream>>>(conv_W2, convPh[2], convPl[2], HID_C, HID_C);
    pack_w_kernel<<<(HID_C / 32) * (OUT_C / 16), 64, 0, stream>>>(out_W, outPh, outPl, HID_C, OUT_C);

    const int gemm_grid = (N_NODES + 127) / 128;  // 391
    const int agg_grid = (N_NODES + 3) / 4;       // 12500

    // Projection: h = x @ proj_W + proj_b  -> hi/lo
    gemm_mfma_kernel<IN_C, HID_C, 1, true><<<gemm_grid, 256, 0, stream>>>(
        x, nullptr, nullptr, projPh, projPl, proj_b, nullptr, nullptr, hHi, hLo, N_NODES);

    // 3 GCN layers
    ushort* Wh_[3] = {convPh[0], convPh[1], convPh[2]};
    ushort* Wl_[3] = {convPl[0], convPl[1], convPl[2]};
    const float* bs_[3] = {conv_b0, conv_b1, conv_b2};
    for (int l = 0; l < 3; l++) {
        // g[node][128] = fp16(dis[node] * (h @ W)[node])
        gemm_mfma_kernel<HID_C, HID_C, 2, false><<<gemm_grid, 256, 0, stream>>>(
            nullptr, hHi, hLo, Wh_[l], Wl_[l], nullptr, dis, (float*)g, nullptr, nullptr, N_NODES);
        aggregate_kernel<<<agg_grid, 256, 0, stream>>>(
            g, row_ptr, csr_src, dis, bs_[l], hHi, hLo);
    }

    // Output: out = h @ out_W + out_b (fp32)
    gemm_mfma_kernel<HID_C, OUT_C, 0, false><<<gemm_grid, 256, 0, stream>>>(
        nullptr, hHi, hLo, outPh, outPl, out_b, nullptr, out, nullptr, nullptr, N_NODES);
}